// Round 1
// baseline (134.829 us; speedup 1.0000x reference)
//
#include <hip/hip_runtime.h>
#include <hip/hip_bf16.h>
#include <math.h>

constexpr int B = 4;
constexpr int N = 1024;
constexpr int F = 64;
constexpr float NEGINF = -9000000000000000.0f;

// ---------------- Kernel 1: hp = h@lin_w^T + b ; u = hp@W1^T ; v = hp@W2^T ----
// 64 blocks x 256 threads; each block does a 64-row tile. vT stored transposed.
__global__ __launch_bounds__(256) void gat_prep(
    const float* __restrict__ h, const float* __restrict__ lin_w,
    const float* __restrict__ lin_b, const float* __restrict__ W_w,
    float* __restrict__ hp, float* __restrict__ ug, float* __restrict__ vT) {
  __shared__ float hT[64 * 68];   // hT[k][n], stride 68 (bank spread + f4 align)
  __shared__ float wT[64 * 68];   // wT[k][f] = lin_w[f][k]
  __shared__ float w1T[64 * 68];  // w1T[k][o]
  __shared__ float w2T[64 * 68];
  __shared__ float hpT[64 * 68];  // hp transposed for the u/v pass
  const int b = blockIdx.x >> 4;
  const int n0 = (blockIdx.x & 15) << 6;
  const int tid = threadIdx.x;

  for (int idx = tid; idx < 4096; idx += 256) {
    const int r = idx >> 6, c = idx & 63;
    hT[c * 68 + r] = h[((b << 10) + n0 + r) * 64 + c];
    wT[c * 68 + r] = lin_w[idx];
    w1T[c * 68 + r] = W_w[r * 128 + c];
    w2T[c * 68 + r] = W_w[r * 128 + 64 + c];
  }
  __syncthreads();

  const int tf = tid & 15, tn = tid >> 4;  // thread computes 4n x 4f block
  float acc[4][4];
#pragma unroll
  for (int q = 0; q < 4; ++q)
#pragma unroll
    for (int r = 0; r < 4; ++r) acc[q][r] = lin_b[tf * 4 + r];

#pragma unroll 4
  for (int k = 0; k < 64; ++k) {
    const float4 ha = *(const float4*)&hT[k * 68 + tn * 4];
    const float4 wa = *(const float4*)&wT[k * 68 + tf * 4];
    const float hv[4] = {ha.x, ha.y, ha.z, ha.w};
    const float wv[4] = {wa.x, wa.y, wa.z, wa.w};
#pragma unroll
    for (int q = 0; q < 4; ++q)
#pragma unroll
      for (int r = 0; r < 4; ++r) acc[q][r] = fmaf(hv[q], wv[r], acc[q][r]);
  }
#pragma unroll
  for (int q = 0; q < 4; ++q) {
    const float4 o4 = make_float4(acc[q][0], acc[q][1], acc[q][2], acc[q][3]);
    *(float4*)&hp[((b << 10) + n0 + tn * 4 + q) * 64 + tf * 4] = o4;
#pragma unroll
    for (int r = 0; r < 4; ++r) hpT[(tf * 4 + r) * 68 + tn * 4 + q] = acc[q][r];
  }
  __syncthreads();

  float au[4][4], av[4][4];
#pragma unroll
  for (int q = 0; q < 4; ++q)
#pragma unroll
    for (int r = 0; r < 4; ++r) { au[q][r] = 0.f; av[q][r] = 0.f; }

#pragma unroll 4
  for (int k = 0; k < 64; ++k) {
    const float4 ha = *(const float4*)&hpT[k * 68 + tn * 4];
    const float4 w1 = *(const float4*)&w1T[k * 68 + tf * 4];
    const float4 w2 = *(const float4*)&w2T[k * 68 + tf * 4];
    const float hv[4] = {ha.x, ha.y, ha.z, ha.w};
    const float v1[4] = {w1.x, w1.y, w1.z, w1.w};
    const float v2[4] = {w2.x, w2.y, w2.z, w2.w};
#pragma unroll
    for (int q = 0; q < 4; ++q)
#pragma unroll
      for (int r = 0; r < 4; ++r) {
        au[q][r] = fmaf(hv[q], v1[r], au[q][r]);
        av[q][r] = fmaf(hv[q], v2[r], av[q][r]);
      }
  }
#pragma unroll
  for (int q = 0; q < 4; ++q) {
    const float4 o4 = make_float4(au[q][0], au[q][1], au[q][2], au[q][3]);
    *(float4*)&ug[((b << 10) + n0 + tn * 4 + q) * 64 + tf * 4] = o4;
  }
  // v -> LDS transposed (reuse hT), then coalesced copy out
#pragma unroll
  for (int q = 0; q < 4; ++q)
#pragma unroll
    for (int r = 0; r < 4; ++r) hT[(tf * 4 + r) * 68 + tn * 4 + q] = av[q][r];
  __syncthreads();
  for (int idx = tid; idx < 4096; idx += 256) {
    const int o = idx >> 6, n = idx & 63;
    vT[((b << 6) + o) * N + n0 + n] = hT[o * 68 + n];
  }
}

// ---------------- Kernel 2: fused e -> mask -> softmax -> PV -> ELU ----------
// block = (b, 8-row i-tile); 512 blocks x 256 threads.
__global__ __launch_bounds__(256) void gat_attn(
    const float* __restrict__ ug, const float* __restrict__ vT,
    const float* __restrict__ hp, const int* __restrict__ adj,
    const float* __restrict__ a, float* __restrict__ out) {
  __shared__ float e_s[N * 12];       // [j][12] (8 rows + pad): 48 KB
  __shared__ float u_s[64 * 8];       // [f][i]
  __shared__ float a_s[64];
  __shared__ float red_s[4 * 8 * 64]; // [g][i][f]
  __shared__ float rinv_s[8];

  const int b = blockIdx.x >> 7;
  const int i0 = (blockIdx.x & 127) << 3;
  const int tid = threadIdx.x;

  if (tid < 64) a_s[tid] = a[tid];
  for (int idx = tid; idx < 512; idx += 256)
    u_s[(idx & 63) * 8 + (idx >> 6)] =
        ug[((b << 10) + i0 + (idx >> 6)) * 64 + (idx & 63)];
  __syncthreads();

  // ---- Phase 1: e[i][k] for j = tid + 256k -------------------------------
  float e[8][4];
#pragma unroll
  for (int i = 0; i < 8; ++i)
#pragma unroll
    for (int k = 0; k < 4; ++k) e[i][k] = 0.f;

  const float* vb = vT + (b << 6) * N;
#pragma unroll 2
  for (int f = 0; f < 64; ++f) {
    const float ap = a_s[f];
    float vv[4];
#pragma unroll
    for (int k = 0; k < 4; ++k) vv[k] = vb[(f << 10) + tid + (k << 8)];
    const float4 ua = *(const float4*)&u_s[f * 8];
    const float4 ub = *(const float4*)&u_s[f * 8 + 4];
    const float uu[8] = {ua.x, ua.y, ua.z, ua.w, ub.x, ub.y, ub.z, ub.w};
#pragma unroll
    for (int i = 0; i < 8; ++i)
#pragma unroll
      for (int k = 0; k < 4; ++k) {
        const float t = uu[i] + vv[k];
        e[i][k] = fmaf(ap, fmaxf(t, 0.2f * t), e[i][k]);  // a_f * leakyrelu
      }
  }
  const int* adjb = adj + ((b << 10) + i0) * N;
#pragma unroll
  for (int i = 0; i < 8; ++i)
#pragma unroll
    for (int k = 0; k < 4; ++k) {
      const int ad = adjb[i * N + tid + (k << 8)];
      e_s[(tid + (k << 8)) * 12 + i] = ad > 0 ? e[i][k] : NEGINF;
    }
  __syncthreads();

  // ---- Phase 2: softmax over j per row (wave w handles rows 2w, 2w+1) ----
  const int lane = tid & 63, w = tid >> 6;
#pragma unroll
  for (int ii = 0; ii < 2; ++ii) {
    const int i = (w << 1) + ii;
    float m = -INFINITY;
#pragma unroll
    for (int mm = 0; mm < 16; ++mm) m = fmaxf(m, e_s[(lane + (mm << 6)) * 12 + i]);
#pragma unroll
    for (int off = 32; off; off >>= 1) m = fmaxf(m, __shfl_xor(m, off));
    float s = 0.f;
#pragma unroll
    for (int mm = 0; mm < 16; ++mm) {
      const int idx = (lane + (mm << 6)) * 12 + i;
      const float p = __expf(e_s[idx] - m);
      e_s[idx] = p;
      s += p;
    }
#pragma unroll
    for (int off = 32; off; off >>= 1) s += __shfl_xor(s, off);
    if (lane == 0) rinv_s[i] = 1.0f / s;
  }
  __syncthreads();

  // ---- Phase 3: h' = attn @ hp; thread = (f, j-group) --------------------
  const int fl = tid & 63, g = tid >> 6;
  float acc[8];
#pragma unroll
  for (int i = 0; i < 8; ++i) acc[i] = 0.f;
  const float* hpb = hp + ((b << 10) << 6);
#pragma unroll 4
  for (int jj = g << 8; jj < (g << 8) + 256; ++jj) {
    const float hv = hpb[(jj << 6) + fl];
    const float4 p0 = *(const float4*)&e_s[jj * 12];
    const float4 p1 = *(const float4*)&e_s[jj * 12 + 4];
    acc[0] = fmaf(p0.x, hv, acc[0]);
    acc[1] = fmaf(p0.y, hv, acc[1]);
    acc[2] = fmaf(p0.z, hv, acc[2]);
    acc[3] = fmaf(p0.w, hv, acc[3]);
    acc[4] = fmaf(p1.x, hv, acc[4]);
    acc[5] = fmaf(p1.y, hv, acc[5]);
    acc[6] = fmaf(p1.z, hv, acc[6]);
    acc[7] = fmaf(p1.w, hv, acc[7]);
  }
#pragma unroll
  for (int i = 0; i < 8; ++i) red_s[((g << 3) + i) * 64 + fl] = acc[i];
  __syncthreads();

#pragma unroll
  for (int o = 0; o < 2; ++o) {
    const int idx = tid + (o << 8);
    const int i = idx >> 6, f = idx & 63;
    float v = red_s[i * 64 + f] + red_s[(8 + i) * 64 + f] +
              red_s[(16 + i) * 64 + f] + red_s[(24 + i) * 64 + f];
    v *= rinv_s[i];
    out[((b << 10) + i0 + i) * 64 + f] = v > 0.f ? v : expm1f(v);
  }
}

extern "C" void kernel_launch(void* const* d_in, const int* in_sizes, int n_in,
                              void* d_out, int out_size, void* d_ws, size_t ws_size,
                              hipStream_t stream) {
  const float* h = (const float*)d_in[0];
  const int* adj = (const int*)d_in[1];
  const float* lin_w = (const float*)d_in[2];
  const float* lin_b = (const float*)d_in[3];
  const float* W_w = (const float*)d_in[4];
  const float* a = (const float*)d_in[5];
  float* outp = (float*)d_out;

  float* hp = (float*)d_ws;            // B*N*F floats
  float* ug = hp + B * N * F;          // B*N*F floats
  float* vT = ug + B * N * F;          // B*F*N floats (transposed)

  gat_prep<<<dim3(64), dim3(256), 0, stream>>>(h, lin_w, lin_b, W_w, hp, ug, vT);
  gat_attn<<<dim3(512), dim3(256), 0, stream>>>(ug, vT, hp, adj, a, outp);
}